// Round 8
// baseline (344.394 us; speedup 1.0000x reference)
//
#include <hip/hip_runtime.h>
#include <math.h>

#define N 4096
#define TOTAL (N * N)
#define MED_RANK 8388607u  // (TOTAL-1)/2

// monotonic float->uint key
__device__ __forceinline__ unsigned fkey(float f) {
    unsigned u = __float_as_uint(f);
    return (u & 0x80000000u) ? ~u : (u | 0x80000000u);
}

// ============================================================
// Deterministic rank-select over an nbins histogram (nbins = 256*bpt,
// bpt<=8). Pure function of hist[] + rank -> every block that calls it
// gets the same answer. Result broadcast via o2: {bin, remaining rank}.
// ============================================================
__device__ void dev_select(const unsigned* __restrict__ hist, int nbins,
                           unsigned rank, unsigned* sc, volatile unsigned* o2) {
    const int tid = threadIdx.x;
    const int bpt = nbins >> 8;
    unsigned cnt[8];
    unsigned s = 0;
    for (int i = 0; i < bpt; i++) { cnt[i] = hist[tid * bpt + i]; s += cnt[i]; }
    sc[tid] = s;
    __syncthreads();
    for (int off = 1; off < 256; off <<= 1) {
        unsigned v = (tid >= off) ? sc[tid - off] : 0u;
        __syncthreads();
        sc[tid] += v;
        __syncthreads();
    }
    const unsigned incl = sc[tid];
    const unsigned excl = incl - s;
    if (rank >= excl && rank < incl) {
        unsigned r = rank - excl;
        for (int i = 0; i < bpt; i++) {
            if (r < cnt[i]) { o2[0] = (unsigned)(tid * bpt + i); o2[1] = r; break; }
            r -= cnt[i];
        }
    }
    __syncthreads();
}

// ============================================================
// K1: Sobel (sequential fp32, row-major taps) -> fp32 products ->
// 49-tap gaussian as sequential fp32 mul/add in row-major (dy,dx)
// order -> fp32 R (left-assoc). Fused radix-hist pass 1.
// ARITHMETIC IS BIT-EXACT ROUND-5 (validated PASS) — do not alter.
// RT=64 -> 70 iters = 7x10; xs ring depth 7 + #pragma unroll 7 makes
// all slot indices static and turns the accumulator ring-shift into
// register renaming (no v_mov chain, no % math).
// ============================================================
constexpr int RT = 64;

__global__ __launch_bounds__(256) void k1_kernel(
    const float* __restrict__ x, const float* __restrict__ gk,
    float* __restrict__ R, unsigned* __restrict__ hist1) {
    __shared__ float xs[7][264];    // x rows ring: row (by-4+m) -> slot m%7
    __shared__ float ps[3][264];    // fp32 product row (cols bx-3 .. bx+258)
    __shared__ unsigned lh[2048];

    const int tid = threadIdx.x;
    const int bx = blockIdx.x * 256;
    const int by = blockIdx.y * RT;

    for (int i = tid; i < 2048; i += 256) lh[i] = 0;

    // full 49 gaussian weights (uniform address -> SGPRs)
    float w49[49];
    #pragma unroll
    for (int k = 0; k < 49; k++) w49[k] = gk[k];

    // ring accumulators: slot k holds partials for out row r = ri+3-k
    float a0[7], a1[7], a2[7];
    #pragma unroll
    for (int k = 0; k < 7; k++) { a0[k] = 0.0f; a1[k] = 0.0f; a2[k] = 0.0f; }

    #pragma unroll
    for (int pre = 0; pre < 2; pre++) {
        int a = by - 4 + pre;
        for (int e = tid; e < 264; e += 256) {
            int col = bx - 4 + e;
            float v = 0.0f;
            if ((unsigned)a < N && (unsigned)col < N) v = x[(size_t)a * N + col];
            xs[pre][e] = v;
        }
    }

    #pragma unroll 7
    for (int it = 0; it < RT + 6; ++it) {
        const int ri = by - 3 + it;  // product row this iter
        {
            int a = ri + 1;
            int slot = (it + 2) % 7;  // static after unroll-7
            for (int e = tid; e < 264; e += 256) {
                int col = bx - 4 + e;
                float v = 0.0f;
                if ((unsigned)a < N && (unsigned)col < N) v = x[(size_t)a * N + col];
                xs[slot][e] = v;
            }
        }
        __syncthreads();

        {
            const int s0 = it % 7, s1 = (it + 1) % 7, s2 = (it + 2) % 7;
            for (int j = tid; j < 262; j += 256) {
                int pc = bx - 3 + j;
                float pxx = 0.0f, pyy = 0.0f, pxy = 0.0f;
                if ((unsigned)ri < N && (unsigned)pc < N) {
                    float A = xs[s0][j], B = xs[s0][j + 1], C = xs[s0][j + 2];
                    float D = xs[s1][j],                    F = xs[s1][j + 2];
                    float G = xs[s2][j], H = xs[s2][j + 1], I = xs[s2][j + 2];
                    // Ix: sequential fp32, row-major over [[-1,0,1],[-2,0,2],[-1,0,1]]
                    float ix = __fmul_rn(-1.0f, A);
                    ix = __fadd_rn(ix, C);
                    ix = __fadd_rn(ix, __fmul_rn(-2.0f, D));
                    ix = __fadd_rn(ix, __fmul_rn(2.0f, F));
                    ix = __fadd_rn(ix, __fmul_rn(-1.0f, G));
                    ix = __fadd_rn(ix, I);
                    // Iy: sequential fp32, row-major over [[-1,-2,-1],[0,0,0],[1,2,1]]
                    float iy = __fmul_rn(-1.0f, A);
                    iy = __fadd_rn(iy, __fmul_rn(-2.0f, B));
                    iy = __fadd_rn(iy, __fmul_rn(-1.0f, C));
                    iy = __fadd_rn(iy, G);
                    iy = __fadd_rn(iy, __fmul_rn(2.0f, H));
                    iy = __fadd_rn(iy, I);
                    pxx = __fmul_rn(ix, ix);
                    pyy = __fmul_rn(iy, iy);
                    pxy = __fmul_rn(ix, iy);
                }
                ps[0][j] = pxx; ps[1][j] = pyy; ps[2][j] = pxy;
            }
        }
        __syncthreads();

        // sequential fp32 accumulation: slot k <- weight row k (dy=k),
        // dx ascending, separate mul/add (no FMA).
        float p0[7], p1[7], p2[7];
        #pragma unroll
        for (int dx = 0; dx < 7; dx++) {
            p0[dx] = ps[0][tid + dx];
            p1[dx] = ps[1][tid + dx];
            p2[dx] = ps[2][tid + dx];
        }
        #pragma unroll
        for (int k = 0; k < 7; k++) {
            float t0 = a0[k], t1 = a1[k], t2 = a2[k];
            #pragma unroll
            for (int dx = 0; dx < 7; dx++) {
                float w = w49[k * 7 + dx];
                t0 = __fadd_rn(t0, __fmul_rn(w, p0[dx]));
                t1 = __fadd_rn(t1, __fmul_rn(w, p1[dx]));
                t2 = __fadd_rn(t2, __fmul_rn(w, p2[dx]));
            }
            a0[k] = t0; a1[k] = t1; a2[k] = t2;
        }

        int r = ri - 3;
        if (r >= by) {
            float sx2 = a0[6], sy2 = a1[6], sxy = a2[6];
            float tr = __fadd_rn(sx2, sy2);
            float e = __fsub_rn(__fmul_rn(sx2, sy2), __fmul_rn(sxy, sxy));
            float t3 = __fmul_rn(__fmul_rn(0.05f, tr), tr);
            float Rv = __fsub_rn(e, t3);
            R[(size_t)r * N + bx + tid] = Rv;
            atomicAdd(&lh[fkey(Rv) >> 21], 1u);
        }
        #pragma unroll
        for (int k = 6; k > 0; k--) { a0[k] = a0[k - 1]; a1[k] = a1[k - 1]; a2[k] = a2[k - 1]; }
        a0[0] = 0.0f; a1[0] = 0.0f; a2[0] = 0.0f;
    }

    __syncthreads();
    for (int i = tid; i < 2048; i += 256) {
        unsigned c = lh[i];
        if (c) atomicAdd(&hist1[i], c);
    }
}

// ============================================================
// Pass 2: recompute select1 from hist1 per block, then histogram
// key bits 20..10 of elements matching the top-11-bit prefix.
// ============================================================
__global__ __launch_bounds__(256) void hist2_kernel(
    const float4* __restrict__ R4, const unsigned* __restrict__ hist1,
    unsigned* __restrict__ hist2) {
    __shared__ unsigned lh[2048];
    __shared__ unsigned sc[256];
    __shared__ unsigned o2[2];

    for (int i = threadIdx.x; i < 2048; i += 256) lh[i] = 0;
    dev_select(hist1, 2048, MED_RANK, sc, o2);  // internal barriers cover lh init
    const unsigned prefix = o2[0] << 21;

    const int total4 = TOTAL / 4;
    const int stride = gridDim.x * 256;
    for (int i = blockIdx.x * 256 + threadIdx.x; i < total4; i += stride) {
        float4 v = R4[i];
        unsigned k0 = fkey(v.x), k1 = fkey(v.y), k2 = fkey(v.z), k3 = fkey(v.w);
        if ((k0 & 0xFFE00000u) == prefix) atomicAdd(&lh[(k0 >> 10) & 0x7FFu], 1u);
        if ((k1 & 0xFFE00000u) == prefix) atomicAdd(&lh[(k1 >> 10) & 0x7FFu], 1u);
        if ((k2 & 0xFFE00000u) == prefix) atomicAdd(&lh[(k2 >> 10) & 0x7FFu], 1u);
        if ((k3 & 0xFFE00000u) == prefix) atomicAdd(&lh[(k3 >> 10) & 0x7FFu], 1u);
    }
    __syncthreads();
    for (int i = threadIdx.x; i < 2048; i += 256) {
        unsigned c = lh[i];
        if (c) atomicAdd(&hist2[i], c);
    }
}

// ============================================================
// Pass 3: recompute select1+select2 per block, then histogram
// key bits 9..0 of elements matching the top-22-bit prefix.
// ============================================================
__global__ __launch_bounds__(256) void hist3_kernel(
    const float4* __restrict__ R4, const unsigned* __restrict__ hist1,
    const unsigned* __restrict__ hist2, unsigned* __restrict__ hist3) {
    __shared__ unsigned lh[1024];
    __shared__ unsigned sc[256];
    __shared__ unsigned o2[2];

    for (int i = threadIdx.x; i < 1024; i += 256) lh[i] = 0;
    dev_select(hist1, 2048, MED_RANK, sc, o2);
    unsigned bin1 = o2[0], rank1 = o2[1];
    dev_select(hist2, 2048, rank1, sc, o2);
    const unsigned prefix = (bin1 << 21) | (o2[0] << 10);

    const int total4 = TOTAL / 4;
    const int stride = gridDim.x * 256;
    for (int i = blockIdx.x * 256 + threadIdx.x; i < total4; i += stride) {
        float4 v = R4[i];
        unsigned k0 = fkey(v.x), k1 = fkey(v.y), k2 = fkey(v.z), k3 = fkey(v.w);
        if ((k0 & 0xFFFFFC00u) == prefix) atomicAdd(&lh[k0 & 0x3FFu], 1u);
        if ((k1 & 0xFFFFFC00u) == prefix) atomicAdd(&lh[k1 & 0x3FFu], 1u);
        if ((k2 & 0xFFFFFC00u) == prefix) atomicAdd(&lh[k2 & 0x3FFu], 1u);
        if ((k3 & 0xFFFFFC00u) == prefix) atomicAdd(&lh[k3 & 0x3FFu], 1u);
    }
    __syncthreads();
    for (int i = threadIdx.x; i < 1024; i += 256) {
        unsigned c = lh[i];
        if (c) atomicAdd(&hist3[i], c);
    }
}

// ============================================================
// K2: recompute select1+2+3 per block -> exact median; threshold +
// 7x7 separable max-pool + NMS (fp32). 64x64 tile per 256 threads.
// fmaxf is exact and NaN-free here, so tap order is free.
// ============================================================
__global__ __launch_bounds__(256) void maxpool_kernel(
    const float* __restrict__ R, const unsigned* __restrict__ hist1,
    const unsigned* __restrict__ hist2, const unsigned* __restrict__ hist3,
    float* __restrict__ out) {
    __shared__ float rt[70 * 72];   // thresholded tile, halo 3, stride 72
    __shared__ float rm[70 * 64];   // row-max
    __shared__ unsigned sc[256];
    __shared__ unsigned o2[2];

    dev_select(hist1, 2048, MED_RANK, sc, o2);
    unsigned bin1 = o2[0], rank1 = o2[1];
    dev_select(hist2, 2048, rank1, sc, o2);
    unsigned bin2 = o2[0], rank2 = o2[1];
    dev_select(hist3, 1024, rank2, sc, o2);
    const unsigned key = (bin1 << 21) | (bin2 << 10) | o2[0];
    const unsigned mu = (key & 0x80000000u) ? (key ^ 0x80000000u) : ~key;
    const float med = __uint_as_float(mu);

    const int tid = threadIdx.x;
    const int bx = blockIdx.x * 64, by = blockIdx.y * 64;

    for (int i = tid; i < 70 * 70; i += 256) {
        int r = i / 70, c = i % 70;
        int gr = by - 3 + r, gc = bx - 3 + c;
        float v = -INFINITY;
        if ((unsigned)gr < N && (unsigned)gc < N) {
            v = R[(size_t)gr * N + gc];
            v = (v < med) ? 0.0f : v;
        }
        rt[r * 72 + c] = v;
    }
    __syncthreads();

    for (int i = tid; i < 70 * 64; i += 256) {
        int r = i / 64, c = i % 64;
        const float* p = &rt[r * 72 + c];
        float m = p[0];
        #pragma unroll
        for (int dx = 1; dx < 7; dx++) m = fmaxf(m, p[dx]);
        rm[i] = m;
    }
    __syncthreads();

    for (int i = tid; i < 64 * 64; i += 256) {
        int r = i / 64, c = i % 64;
        float m = rm[r * 64 + c];
        #pragma unroll
        for (int dy = 1; dy < 7; dy++) m = fmaxf(m, rm[(r + dy) * 64 + c]);
        float v = rt[(r + 3) * 72 + (c + 3)];
        out[(size_t)(by + r) * N + (bx + c)] = (v == m) ? v : 0.0f;
    }
}

// ============================================================
extern "C" void kernel_launch(void* const* d_in, const int* in_sizes, int n_in,
                              void* d_out, int out_size, void* d_ws, size_t ws_size,
                              hipStream_t stream) {
    const float* x = (const float*)d_in[0];
    const float* gk = (const float*)d_in[1];
    float* out = (float*)d_out;

    char* ws = (char*)d_ws;
    float* R = (float*)ws;                                 // 64 MB
    unsigned* hist1 = (unsigned*)(ws + (size_t)TOTAL * 4); // 2048 u32
    unsigned* hist2 = hist1 + 2048;                        // 2048 u32
    unsigned* hist3 = hist2 + 2048;                        // 1024 u32

    hipMemsetAsync(hist1, 0, (2048 + 2048 + 1024) * 4, stream);

    k1_kernel<<<dim3(N / 256, N / RT), 256, 0, stream>>>(x, gk, R, hist1);

    const float4* R4 = (const float4*)R;
    hist2_kernel<<<1024, 256, 0, stream>>>(R4, hist1, hist2);
    hist3_kernel<<<1024, 256, 0, stream>>>(R4, hist1, hist2, hist3);
    maxpool_kernel<<<dim3(N / 64, N / 64), 256, 0, stream>>>(R, hist1, hist2, hist3, out);
}

// Round 9
// 317.683 us; speedup vs baseline: 1.0841x; 1.0841x over previous
//
#include <hip/hip_runtime.h>
#include <math.h>

#define N 4096
#define TOTAL (N * N)
#define MED_RANK 8388607u  // (TOTAL-1)/2

// monotonic float->uint key
__device__ __forceinline__ unsigned fkey(float f) {
    unsigned u = __float_as_uint(f);
    return (u & 0x80000000u) ? ~u : (u | 0x80000000u);
}

// Sobel + products — EXACT round-5-validated fp32 sequence. Do not alter.
__device__ __forceinline__ void sobel3(float A, float B, float C,
                                       float D, float F,
                                       float G, float H, float I,
                                       float& pxx, float& pyy, float& pxy) {
    float ix = __fmul_rn(-1.0f, A);
    ix = __fadd_rn(ix, C);
    ix = __fadd_rn(ix, __fmul_rn(-2.0f, D));
    ix = __fadd_rn(ix, __fmul_rn(2.0f, F));
    ix = __fadd_rn(ix, __fmul_rn(-1.0f, G));
    ix = __fadd_rn(ix, I);
    float iy = __fmul_rn(-1.0f, A);
    iy = __fadd_rn(iy, __fmul_rn(-2.0f, B));
    iy = __fadd_rn(iy, __fmul_rn(-1.0f, C));
    iy = __fadd_rn(iy, G);
    iy = __fadd_rn(iy, __fmul_rn(2.0f, H));
    iy = __fadd_rn(iy, I);
    pxx = __fmul_rn(ix, ix);
    pyy = __fmul_rn(iy, iy);
    pxy = __fmul_rn(ix, iy);
}

// ============================================================
// K1: 512-wide tile, 2 consecutive columns per thread (float2),
// all LDS traffic as 8B ds_read_b64/ds_write_b64.
//   xs[slot][e] = x[row][bx-5+e], e=0..523 (window for product pair
//     j0=2t starts at e=2t -> 8B aligned)
//   ps[ch][j]   = product at col bx+j-4, j=0..519
// Thread t: products j=2t,2t+1 (cols 2t-4,2t-3; t<260 via 2nd pass
// of threads 0..3); outputs cols 2t,2t+1 reading ps[2t+1..2t+8]
// (5 aligned b64 per channel). Per-column arithmetic sequence is
// bit-identical to round 5 (PASS, absmax 2.0).
// Fused radix-hist pass 1. RT=32 -> grid (8,128)=1024 blocks (4/CU).
// ============================================================
constexpr int RT = 32;
constexpr int W = 512;

__global__ __launch_bounds__(256) void k1_kernel(
    const float* __restrict__ x, const float* __restrict__ gk,
    float* __restrict__ R, unsigned* __restrict__ hist1) {
    __shared__ __align__(16) float xs[3][524];
    __shared__ __align__(16) float ps[3][520];
    __shared__ unsigned lh[2048];

    const int tid = threadIdx.x;
    const int bx = blockIdx.x * W;
    const int by = blockIdx.y * RT;

    for (int i = tid; i < 2048; i += 256) lh[i] = 0;

    // full 49 gaussian weights (uniform -> scalar regs)
    float w49[49];
    #pragma unroll
    for (int k = 0; k < 49; k++) w49[k] = gk[k];

    // ring accumulators: slot k holds partials for out row r = ri+3-k
    float2 a0[7], a1[7], a2[7];
    #pragma unroll
    for (int k = 0; k < 7; k++) {
        a0[k] = make_float2(0.0f, 0.0f);
        a1[k] = make_float2(0.0f, 0.0f);
        a2[k] = make_float2(0.0f, 0.0f);
    }

    #define LOAD_ROW(arow, slot)                                             \
        for (int e2 = tid; e2 < 262; e2 += 256) {                            \
            int e = 2 * e2;                                                  \
            int col = bx - 5 + e;                                            \
            float v0 = 0.0f, v1 = 0.0f;                                      \
            if ((unsigned)(arow) < N) {                                      \
                if ((unsigned)col < N) v0 = x[(size_t)(arow)*N + col];       \
                if ((unsigned)(col + 1) < N) v1 = x[(size_t)(arow)*N + col + 1]; \
            }                                                                \
            *(float2*)&xs[slot][e] = make_float2(v0, v1);                    \
        }

    LOAD_ROW(by - 4, 0)
    LOAD_ROW(by - 3, 1)

    for (int it = 0; it < RT + 6; ++it) {
        const int ri = by - 3 + it;  // product row this iter
        {
            int arow = ri + 1;
            int slot = (it + 2) % 3;
            LOAD_ROW(arow, slot)
        }
        __syncthreads();  // B1: xs ready

        {
            const int s0 = it % 3, s1 = (it + 1) % 3, s2 = (it + 2) % 3;
            const bool rowv = (unsigned)ri < N;
            for (int t = tid; t < 260; t += 256) {
                int e = 2 * t;
                float2 r0a = *(const float2*)&xs[s0][e];
                float2 r0b = *(const float2*)&xs[s0][e + 2];
                float2 r1a = *(const float2*)&xs[s1][e];
                float2 r1b = *(const float2*)&xs[s1][e + 2];
                float2 r2a = *(const float2*)&xs[s2][e];
                float2 r2b = *(const float2*)&xs[s2][e + 2];
                float pxx0 = 0.0f, pyy0 = 0.0f, pxy0 = 0.0f;
                float pxx1 = 0.0f, pyy1 = 0.0f, pxy1 = 0.0f;
                if (rowv) {
                    if ((unsigned)(bx + 2 * t - 4) < N)
                        sobel3(r0a.x, r0a.y, r0b.x, r1a.x, r1b.x,
                               r2a.x, r2a.y, r2b.x, pxx0, pyy0, pxy0);
                    if ((unsigned)(bx + 2 * t - 3) < N)
                        sobel3(r0a.y, r0b.x, r0b.y, r1a.y, r1b.y,
                               r2a.y, r2b.x, r2b.y, pxx1, pyy1, pxy1);
                }
                *(float2*)&ps[0][e] = make_float2(pxx0, pxx1);
                *(float2*)&ps[1][e] = make_float2(pyy0, pyy1);
                *(float2*)&ps[2][e] = make_float2(pxy0, pxy1);
            }
        }
        __syncthreads();  // B2: ps ready (also protects xs slot reuse)

        // gather window ps[2*tid .. 2*tid+9] per channel (5 aligned b64 each)
        float q0[10], q1[10], q2[10];
        #pragma unroll
        for (int i = 0; i < 5; i++) {
            float2 v0 = *(const float2*)&ps[0][2 * (tid + i)];
            float2 v1 = *(const float2*)&ps[1][2 * (tid + i)];
            float2 v2 = *(const float2*)&ps[2][2 * (tid + i)];
            q0[2 * i] = v0.x; q0[2 * i + 1] = v0.y;
            q1[2 * i] = v1.x; q1[2 * i + 1] = v1.y;
            q2[2 * i] = v2.x; q2[2 * i + 1] = v2.y;
        }
        // sequential fp32 accumulation, row-major (dy=k, dx asc), no FMA —
        // per-column order identical to round 5.
        #pragma unroll
        for (int k = 0; k < 7; k++) {
            float t0x = a0[k].x, t0y = a0[k].y;
            float t1x = a1[k].x, t1y = a1[k].y;
            float t2x = a2[k].x, t2y = a2[k].y;
            #pragma unroll
            for (int dx = 0; dx < 7; dx++) {
                float w = w49[k * 7 + dx];
                t0x = __fadd_rn(t0x, __fmul_rn(w, q0[1 + dx]));
                t0y = __fadd_rn(t0y, __fmul_rn(w, q0[2 + dx]));
                t1x = __fadd_rn(t1x, __fmul_rn(w, q1[1 + dx]));
                t1y = __fadd_rn(t1y, __fmul_rn(w, q1[2 + dx]));
                t2x = __fadd_rn(t2x, __fmul_rn(w, q2[1 + dx]));
                t2y = __fadd_rn(t2y, __fmul_rn(w, q2[2 + dx]));
            }
            a0[k] = make_float2(t0x, t0y);
            a1[k] = make_float2(t1x, t1y);
            a2[k] = make_float2(t2x, t2y);
        }

        int r = ri - 3;
        if (r >= by) {
            // fp32 R, left-assoc (round-5 sequence), per column
            float Rx, Ry;
            {
                float sx2 = a0[6].x, sy2 = a1[6].x, sxy = a2[6].x;
                float tr = __fadd_rn(sx2, sy2);
                float e = __fsub_rn(__fmul_rn(sx2, sy2), __fmul_rn(sxy, sxy));
                float t3 = __fmul_rn(__fmul_rn(0.05f, tr), tr);
                Rx = __fsub_rn(e, t3);
            }
            {
                float sx2 = a0[6].y, sy2 = a1[6].y, sxy = a2[6].y;
                float tr = __fadd_rn(sx2, sy2);
                float e = __fsub_rn(__fmul_rn(sx2, sy2), __fmul_rn(sxy, sxy));
                float t3 = __fmul_rn(__fmul_rn(0.05f, tr), tr);
                Ry = __fsub_rn(e, t3);
            }
            *(float2*)&R[(size_t)r * N + bx + 2 * tid] = make_float2(Rx, Ry);
            atomicAdd(&lh[fkey(Rx) >> 21], 1u);
            atomicAdd(&lh[fkey(Ry) >> 21], 1u);
        }
        #pragma unroll
        for (int k = 6; k > 0; k--) { a0[k] = a0[k - 1]; a1[k] = a1[k - 1]; a2[k] = a2[k - 1]; }
        a0[0] = make_float2(0.0f, 0.0f);
        a1[0] = make_float2(0.0f, 0.0f);
        a2[0] = make_float2(0.0f, 0.0f);
    }

    __syncthreads();
    for (int i = tid; i < 2048; i += 256) {
        unsigned c = lh[i];
        if (c) atomicAdd(&hist1[i], c);
    }
}

// ============================================================
// Histogram passes 2,3 over fp32 keys.
// ============================================================
__global__ __launch_bounds__(256) void hist_kernel(
    const float4* __restrict__ R4, unsigned* __restrict__ hist,
    const unsigned* __restrict__ state,
    unsigned match_mask, int bin_shift, unsigned bin_mask, int nbins) {
    __shared__ unsigned lh[2048];
    for (int i = threadIdx.x; i < nbins; i += 256) lh[i] = 0;
    __syncthreads();

    const unsigned prefix = state[0] & match_mask;
    const int total4 = TOTAL / 4;
    const int stride = gridDim.x * 256;

    for (int i = blockIdx.x * 256 + threadIdx.x; i < total4; i += stride) {
        float4 v = R4[i];
        unsigned k0 = fkey(v.x), k1 = fkey(v.y), k2 = fkey(v.z), k3 = fkey(v.w);
        if ((k0 & match_mask) == prefix) atomicAdd(&lh[(k0 >> bin_shift) & bin_mask], 1u);
        if ((k1 & match_mask) == prefix) atomicAdd(&lh[(k1 >> bin_shift) & bin_mask], 1u);
        if ((k2 & match_mask) == prefix) atomicAdd(&lh[(k2 >> bin_shift) & bin_mask], 1u);
        if ((k3 & match_mask) == prefix) atomicAdd(&lh[(k3 >> bin_shift) & bin_mask], 1u);
    }
    __syncthreads();
    for (int i = threadIdx.x; i < nbins; i += 256) {
        unsigned c = lh[i];
        if (c) atomicAdd(&hist[i], c);
    }
}

// ============================================================
// Select: single block. state[0]=prefix, state[1]=rank,
// state[2]=median float bits (written on last pass).
// ============================================================
__global__ __launch_bounds__(256) void select_kernel(
    const unsigned* __restrict__ hist, unsigned* __restrict__ state,
    int nbins, int prefix_shift, int is_first, int is_last) {
    const int tid = threadIdx.x;
    const int bpt = nbins >> 8;

    const unsigned rank = is_first ? MED_RANK : state[1];
    const unsigned oldpref = is_first ? 0u : state[0];

    unsigned cnt[8];
    unsigned s = 0;
    for (int i = 0; i < bpt; i++) { cnt[i] = hist[tid * bpt + i]; s += cnt[i]; }
    __shared__ unsigned sc[256];
    sc[tid] = s;
    __syncthreads();
    for (int off = 1; off < 256; off <<= 1) {
        unsigned v = (tid >= off) ? sc[tid - off] : 0u;
        __syncthreads();
        sc[tid] += v;
        __syncthreads();
    }
    const unsigned incl = sc[tid];
    const unsigned excl = incl - s;

    if (rank >= excl && rank < incl) {
        unsigned r = rank - excl;
        for (int i = 0; i < bpt; i++) {
            if (r < cnt[i]) {
                unsigned bin = (unsigned)(tid * bpt + i);
                unsigned npref = oldpref | (bin << prefix_shift);
                state[0] = npref;
                state[1] = r;
                if (is_last) {
                    unsigned key = npref;
                    unsigned u = (key & 0x80000000u) ? (key ^ 0x80000000u) : ~key;
                    state[2] = u;
                }
                break;
            }
            r -= cnt[i];
        }
    }
}

// ============================================================
// K2: threshold + 7x7 separable max-pool + NMS (fp32), vectorized.
// rt[r][e] = Rt[by-3+r][bx-4+e] (shift 4 -> all b128 aligned).
// Horizontal pass shares the middle-4 max across 4 outputs.
// fmaxf exact & NaN-free -> tap order free.
// ============================================================
__global__ __launch_bounds__(256) void maxpool_kernel(
    const float* __restrict__ R, const unsigned* __restrict__ state,
    float* __restrict__ out) {
    __shared__ __align__(16) float rt[70 * 72];  // 70 rows x 72 (71 used)
    __shared__ __align__(16) float rm[70 * 64];  // horizontal max

    const float med = __uint_as_float(state[2]);
    const int tid = threadIdx.x;
    const int bx = blockIdx.x * 64, by = blockIdx.y * 64;

    // load + threshold (OOB = -inf, never thresholded)
    for (int i = tid; i < 70 * 18; i += 256) {
        int r = i / 18, g = i % 18;
        int gr = by - 3 + r;
        int c0 = bx - 4 + 4 * g;
        float4 v;
        if ((unsigned)gr < N && c0 >= 0 && c0 + 3 < N) {
            v = *(const float4*)&R[(size_t)gr * N + c0];
            v.x = (v.x < med) ? 0.0f : v.x;
            v.y = (v.y < med) ? 0.0f : v.y;
            v.z = (v.z < med) ? 0.0f : v.z;
            v.w = (v.w < med) ? 0.0f : v.w;
        } else {
            float t[4];
            #pragma unroll
            for (int m = 0; m < 4; m++) {
                int c = c0 + m;
                float vv = -INFINITY;
                if ((unsigned)gr < N && (unsigned)c < N) {
                    vv = R[(size_t)gr * N + c];
                    vv = (vv < med) ? 0.0f : vv;
                }
                t[m] = vv;
            }
            v = make_float4(t[0], t[1], t[2], t[3]);
        }
        *(float4*)&rt[r * 72 + 4 * g] = v;
    }
    __syncthreads();

    // horizontal 7-tap max: out col c=4u+m needs rt e = c+1 .. c+7
    for (int i = tid; i < 70 * 16; i += 256) {
        int r = i / 16, u = i % 16;
        const float* p = &rt[r * 72 + 4 * u];
        float4 A = *(const float4*)&p[0];
        float4 B = *(const float4*)&p[4];
        float4 C = *(const float4*)&p[8];
        float core = fmaxf(fmaxf(B.x, B.y), fmaxf(B.z, B.w));
        float m0 = fmaxf(fmaxf(A.y, A.z), fmaxf(A.w, core));
        float m1 = fmaxf(fmaxf(A.z, A.w), fmaxf(core, C.x));
        float m2 = fmaxf(A.w, fmaxf(core, fmaxf(C.x, C.y)));
        float m3 = fmaxf(core, fmaxf(fmaxf(C.x, C.y), C.z));
        *(float4*)&rm[r * 64 + 4 * u] = make_float4(m0, m1, m2, m3);
    }
    __syncthreads();

    // vertical 7-tap max + NMS + store
    for (int i = tid; i < 64 * 16; i += 256) {
        int r = i / 16, u = i % 16;
        float4 m = *(const float4*)&rm[r * 64 + 4 * u];
        #pragma unroll
        for (int dy = 1; dy < 7; dy++) {
            float4 z = *(const float4*)&rm[(r + dy) * 64 + 4 * u];
            m.x = fmaxf(m.x, z.x);
            m.y = fmaxf(m.y, z.y);
            m.z = fmaxf(m.z, z.z);
            m.w = fmaxf(m.w, z.w);
        }
        float4 v = *(const float4*)&rt[(r + 3) * 72 + 4 * u + 4];
        float4 o;
        o.x = (v.x == m.x) ? v.x : 0.0f;
        o.y = (v.y == m.y) ? v.y : 0.0f;
        o.z = (v.z == m.z) ? v.z : 0.0f;
        o.w = (v.w == m.w) ? v.w : 0.0f;
        *(float4*)&out[(size_t)(by + r) * N + bx + 4 * u] = o;
    }
}

// ============================================================
extern "C" void kernel_launch(void* const* d_in, const int* in_sizes, int n_in,
                              void* d_out, int out_size, void* d_ws, size_t ws_size,
                              hipStream_t stream) {
    const float* x = (const float*)d_in[0];
    const float* gk = (const float*)d_in[1];
    float* out = (float*)d_out;

    char* ws = (char*)d_ws;
    float* R = (float*)ws;                                 // 64 MB
    unsigned* hist1 = (unsigned*)(ws + (size_t)TOTAL * 4); // 2048 u32
    unsigned* hist2 = hist1 + 2048;                        // 2048 u32
    unsigned* hist3 = hist2 + 2048;                        // 1024 u32
    unsigned* state = hist3 + 1024;                        // 4 u32

    hipMemsetAsync(hist1, 0, (2048 + 2048 + 1024) * 4, stream);

    k1_kernel<<<dim3(N / W, N / RT), 256, 0, stream>>>(x, gk, R, hist1);

    const float4* R4 = (const float4*)R;
    // pass 1: key bits 31..21 (hist fused into K1)
    select_kernel<<<1, 256, 0, stream>>>(hist1, state, 2048, 21, 1, 0);
    // pass 2: key bits 20..10
    hist_kernel<<<1024, 256, 0, stream>>>(R4, hist2, state, 0xFFE00000u, 10, 0x7FFu, 2048);
    select_kernel<<<1, 256, 0, stream>>>(hist2, state, 2048, 10, 0, 0);
    // pass 3: key bits 9..0
    hist_kernel<<<1024, 256, 0, stream>>>(R4, hist3, state, 0xFFFFFC00u, 0, 0x3FFu, 1024);
    select_kernel<<<1, 256, 0, stream>>>(hist3, state, 1024, 0, 0, 1);

    maxpool_kernel<<<dim3(N / 64, N / 64), 256, 0, stream>>>(R, state, out);
}